// Round 1
// baseline (1394.561 us; speedup 1.0000x reference)
//
#include <hip/hip_runtime.h>

#define Sn 500
#define Dn 10
#define Tn 40
#define FPn 3
#define FTn 512
#define Hn 64
#define G3 192
#define NHn 4

typedef __attribute__((ext_vector_type(8))) short bf8_t;   // 8 x bf16 bits
typedef __attribute__((ext_vector_type(4))) float f4_t;

__device__ __forceinline__ unsigned short f2bf(float f) {
    union { float f; unsigned int u; } v; v.f = f;
    unsigned int r = v.u + 0x7fffu + ((v.u >> 16) & 1u);   // round-to-nearest-even
    return (unsigned short)(r >> 16);
}
__device__ __forceinline__ float bflo(unsigned int u) {
    union { unsigned int u; float f; } v; v.u = u << 16; return v.f;
}
__device__ __forceinline__ float bfhi(unsigned int u) {
    union { unsigned int u; float f; } v; v.u = u & 0xffff0000u; return v.f;
}
__device__ __forceinline__ float sigmoidf_(float x) { return 1.f / (1.f + __expf(-x)); }
__device__ __forceinline__ float tanhf_(float x) {
    x = fminf(15.f, fmaxf(-15.f, x));
    float e = __expf(2.f * x);
    return (e - 1.f) / (e + 1.f);
}

// ---------------------------------------------------------------------------
// Text encoder: one block per (stock, day). Computes gi = x@Wih + bih via bf16
// MFMA, then 40-step GRU recurrence with Whh staged bf16 in LDS (transposed +
// XOR-swizzled), then additive-attention pooling -> news[s,d,:].
// ---------------------------------------------------------------------------
__global__ __launch_bounds__(256) void text_enc(
    const float* __restrict__ text, const float* __restrict__ Wih,
    const float* __restrict__ Whh, const float* __restrict__ bih,
    const float* __restrict__ bhh, const float* __restrict__ Wa,
    const float* __restrict__ va, float* __restrict__ news)
{
    __shared__ __align__(16) float gi[Tn][G3];              // 30720 B
    __shared__ __align__(16) unsigned char whhT[G3 * Hn * 2]; // bf16 [j][i] swizzled, 24576 B
    __shared__ __align__(16) float hs[Tn][Hn];              // 10240 B
    __shared__ __align__(16) float hcur[Hn];
    __shared__ float gh[G3];
    __shared__ float red[160];
    __shared__ float scb[Tn], alb[Tn];
    __shared__ float ssum;

    const int blk = blockIdx.x;
    const int s = blk / Dn;
    const int tid = threadIdx.x;
    const int lane = tid & 63, w = tid >> 6;

    const float* Wihs = Wih + (size_t)s * FTn * G3;
    const float* Whhs = Whh + (size_t)s * Hn * G3;
    const float* xblk = text + (size_t)blk * Tn * FTn;

    // stage Whh^T as bf16, swizzled: byte = j*128 + ((2i) ^ ((j&7)<<4))
    for (int e = tid; e < Hn * G3; e += 256) {
        int i = e / G3, j = e - i * G3;
        *(unsigned short*)(whhT + j * 128 + (((i * 2) ^ ((j & 7) << 4)))) = f2bf(Whhs[e]);
    }
    if (tid < Hn) hcur[tid] = 0.f;

    // ---- gi via MFMA: M=40(pad48), N=192, K=512. wave w owns n-tiles 3w..3w+2
    f4_t acc[3][3];
    #pragma unroll
    for (int a = 0; a < 3; a++)
        #pragma unroll
        for (int b = 0; b < 3; b++) acc[a][b] = (f4_t){0.f, 0.f, 0.f, 0.f};
    const int rt = lane & 15, kg = lane >> 4;
    for (int kk = 0; kk < FTn / 32; ++kk) {
        const int kbase = kk * 32 + kg * 8;
        bf8_t afr[3], bfr[3];
        #pragma unroll
        for (int mt = 0; mt < 3; ++mt) {
            int r = mt * 16 + rt;
            if (r < Tn) {
                const float* p = xblk + r * FTn + kbase;
                f4_t v0 = *(const f4_t*)p, v1 = *(const f4_t*)(p + 4);
                afr[mt][0] = (short)f2bf(v0[0]); afr[mt][1] = (short)f2bf(v0[1]);
                afr[mt][2] = (short)f2bf(v0[2]); afr[mt][3] = (short)f2bf(v0[3]);
                afr[mt][4] = (short)f2bf(v1[0]); afr[mt][5] = (short)f2bf(v1[1]);
                afr[mt][6] = (short)f2bf(v1[2]); afr[mt][7] = (short)f2bf(v1[3]);
            } else {
                #pragma unroll
                for (int b = 0; b < 8; b++) afr[mt][b] = 0;
            }
        }
        #pragma unroll
        for (int nc = 0; nc < 3; ++nc) {
            const int col = (w * 3 + nc) * 16 + rt;
            const float* bp = Wihs + (size_t)kbase * G3 + col;
            #pragma unroll
            for (int b = 0; b < 8; b++) bfr[nc][b] = (short)f2bf(bp[b * G3]);
        }
        #pragma unroll
        for (int mt = 0; mt < 3; ++mt)
            #pragma unroll
            for (int nc = 0; nc < 3; ++nc)
                acc[mt][nc] = __builtin_amdgcn_mfma_f32_16x16x32_bf16(afr[mt], bfr[nc], acc[mt][nc], 0, 0, 0);
    }
    const float* bihs = bih + (size_t)s * G3;
    #pragma unroll
    for (int nc = 0; nc < 3; ++nc) {
        const int col = (w * 3 + nc) * 16 + rt;
        const float bv = bihs[col];
        #pragma unroll
        for (int mt = 0; mt < 3; ++mt) {
            #pragma unroll
            for (int rg = 0; rg < 4; rg++) {
                int r = mt * 16 + kg * 4 + rg;
                if (r < Tn) gi[r][col] = acc[mt][nc][rg] + bv;
            }
        }
    }
    __syncthreads();

    // ---- GRU recurrence, 40 serial steps
    const float* bhhs = bhh + (size_t)s * G3;
    for (int t = 0; t < Tn; t++) {
        if (tid < G3) {
            const int j = tid;
            const int sw = (j & 7) << 4;
            float a = bhhs[j];
            #pragma unroll
            for (int ic = 0; ic < 8; ++ic) {
                uint4 wv = *(const uint4*)(whhT + j * 128 + ((ic * 16) ^ sw));
                f4_t h0 = *(const f4_t*)&hcur[ic * 8];
                f4_t h1 = *(const f4_t*)&hcur[ic * 8 + 4];
                a += bflo(wv.x) * h0[0] + bfhi(wv.x) * h0[1]
                   + bflo(wv.y) * h0[2] + bfhi(wv.y) * h0[3]
                   + bflo(wv.z) * h1[0] + bfhi(wv.z) * h1[1]
                   + bflo(wv.w) * h1[2] + bfhi(wv.w) * h1[3];
            }
            gh[j] = a;
        }
        __syncthreads();
        if (tid < Hn) {
            const int c = tid;
            float r = sigmoidf_(gi[t][c] + gh[c]);
            float z = sigmoidf_(gi[t][Hn + c] + gh[Hn + c]);
            float n = tanhf_(gi[t][2 * Hn + c] + r * gh[2 * Hn + c]);
            float hn = (1.f - z) * n + z * hcur[c];
            hcur[c] = hn;
            hs[t][c] = hn;
        }
        __syncthreads();
    }

    // ---- additive attention pooling over 40 steps
    const float* Was = Wa + (size_t)s * Hn * Hn;
    const float* vas = va + (size_t)s * Hn;
    if (tid < 160) {
        const int t = tid % Tn, q = tid / Tn;
        float part = 0.f;
        for (int k = q * 16; k < q * 16 + 16; ++k) {
            float dot = 0.f;
            #pragma unroll 4
            for (int i = 0; i < Hn; i += 4) {
                f4_t hv = *(const f4_t*)&hs[t][i];
                dot += hv[0] * Was[i * Hn + k] + hv[1] * Was[(i + 1) * Hn + k]
                     + hv[2] * Was[(i + 2) * Hn + k] + hv[3] * Was[(i + 3) * Hn + k];
            }
            part += tanhf_(dot) * vas[k];
        }
        red[tid] = part;
    }
    __syncthreads();
    if (tid < Tn) scb[tid] = red[tid] + red[Tn + tid] + red[2 * Tn + tid] + red[3 * Tn + tid];
    __syncthreads();
    if (tid == 0) {
        float m = -1e30f;
        for (int t = 0; t < Tn; t++) m = fmaxf(m, scb[t]);
        float ss = 0.f;
        for (int t = 0; t < Tn; t++) { float p = __expf(scb[t] - m); alb[t] = p; ss += p; }
        ssum = ss;
    }
    __syncthreads();
    if (tid < Hn) {
        float o = 0.f;
        for (int t = 0; t < Tn; t++) o += alb[t] * hs[t][tid];
        news[(size_t)blk * Hn + tid] = o / ssum;
    }
}

// ---------------------------------------------------------------------------
// Small GRU (price: FIN=3, day-sequence: FIN=64) over D=10 steps + attn pool.
// One block per stock, 192 threads, all f32 (Whh^T f32 swizzled in LDS).
// ---------------------------------------------------------------------------
template<int FIN>
__global__ __launch_bounds__(192) void small_gru(
    const float* __restrict__ xin, const float* __restrict__ Wih,
    const float* __restrict__ Whh, const float* __restrict__ bih,
    const float* __restrict__ bhh, const float* __restrict__ Wa,
    const float* __restrict__ va, float* __restrict__ outv)
{
    __shared__ __align__(16) float whhT[G3 * Hn];   // f32 [j][i] swizzled, 49152 B
    __shared__ float gi[Dn][G3];
    __shared__ float xs[Dn * FIN];
    __shared__ __align__(16) float hs[Dn][Hn];
    __shared__ __align__(16) float hcur[Hn];
    __shared__ float gh[G3];
    __shared__ float red[160];
    __shared__ float scb[Dn], alb[Dn];
    __shared__ float ssum;

    const int s = blockIdx.x, tid = threadIdx.x;
    char* wb = (char*)whhT;

    for (int e = tid; e < Dn * FIN; e += 192) xs[e] = xin[(size_t)s * Dn * FIN + e];
    const float* Whhs = Whh + (size_t)s * Hn * G3;
    for (int e = tid; e < Hn * G3; e += 192) {
        int i = e / G3, j = e - i * G3;
        *(float*)(wb + j * 256 + (((i * 4) ^ ((j & 15) << 4)))) = Whhs[e];
    }
    if (tid < Hn) hcur[tid] = 0.f;
    __syncthreads();

    {   // gi = x @ Wih + bih
        const int j = tid;
        const float* Wihs = Wih + (size_t)s * FIN * G3;
        const float bi = bih[(size_t)s * G3 + j];
        for (int t = 0; t < Dn; t++) {
            float a = bi;
            for (int i = 0; i < FIN; i++) a += xs[t * FIN + i] * Wihs[i * G3 + j];
            gi[t][j] = a;
        }
    }
    __syncthreads();

    const float* bhhs = bhh + (size_t)s * G3;
    for (int t = 0; t < Dn; t++) {
        {
            const int j = tid;
            const int sw = (j & 15) << 4;
            float a = bhhs[j];
            #pragma unroll
            for (int ic = 0; ic < 16; ++ic) {
                f4_t wv = *(const f4_t*)(wb + j * 256 + ((ic * 16) ^ sw));
                f4_t hv = *(const f4_t*)&hcur[ic * 4];
                a += wv[0] * hv[0] + wv[1] * hv[1] + wv[2] * hv[2] + wv[3] * hv[3];
            }
            gh[j] = a;
        }
        __syncthreads();
        if (tid < Hn) {
            const int c = tid;
            float r = sigmoidf_(gi[t][c] + gh[c]);
            float z = sigmoidf_(gi[t][Hn + c] + gh[Hn + c]);
            float n = tanhf_(gi[t][2 * Hn + c] + r * gh[2 * Hn + c]);
            float hn = (1.f - z) * n + z * hcur[c];
            hcur[c] = hn; hs[t][c] = hn;
        }
        __syncthreads();
    }

    const float* Was = Wa + (size_t)s * Hn * Hn;
    const float* vas = va + (size_t)s * Hn;
    if (tid < Dn * 16) {
        const int t = tid >> 4, kc = tid & 15;
        float part = 0.f;
        for (int k = kc * 4; k < kc * 4 + 4; ++k) {
            float dot = 0.f;
            for (int i = 0; i < Hn; i += 4) {
                f4_t hv = *(const f4_t*)&hs[t][i];
                dot += hv[0] * Was[i * Hn + k] + hv[1] * Was[(i + 1) * Hn + k]
                     + hv[2] * Was[(i + 2) * Hn + k] + hv[3] * Was[(i + 3) * Hn + k];
            }
            part += tanhf_(dot) * vas[k];
        }
        red[tid] = part;
    }
    __syncthreads();
    if (tid < Dn) {
        float sc = 0.f;
        for (int kc = 0; kc < 16; kc++) sc += red[tid * 16 + kc];
        scb[tid] = sc;
    }
    __syncthreads();
    if (tid == 0) {
        float m = -1e30f;
        for (int t = 0; t < Dn; t++) m = fmaxf(m, scb[t]);
        float ss = 0.f;
        for (int t = 0; t < Dn; t++) { float p = __expf(scb[t] - m); alb[t] = p; ss += p; }
        ssum = ss;
    }
    __syncthreads();
    if (tid < Hn) {
        float o = 0.f;
        for (int t = 0; t < Dn; t++) o += alb[t] * hs[t][tid];
        outv[(size_t)s * Hn + tid] = o / ssum;
    }
}

// ---------------------------------------------------------------------------
// Bilinear fusion + per-stock q/k projections + blend head. One block/stock.
// combined = tanh(einsum(i,kij,j->k) + bb); q,k = combined@Wq/Wk+b; out_1.
// ---------------------------------------------------------------------------
__global__ __launch_bounds__(256) void bilinear_head(
    const float* __restrict__ Wb, const float* __restrict__ bb,
    const float* __restrict__ Wbl, const float* __restrict__ bbl,
    const float* __restrict__ Wq, const float* __restrict__ bq,
    const float* __restrict__ Wk, const float* __restrict__ bk,
    const float* __restrict__ xprice, const float* __restrict__ tvec,
    float* __restrict__ combined, float* __restrict__ qg,
    float* __restrict__ kg, float* __restrict__ out1)
{
    __shared__ __align__(16) float uT[Hn][Hn];   // u transposed [i][k], 16 KB
    __shared__ float cl[Hn];
    __shared__ float tv[Hn];

    const int s = blockIdx.x, tid = threadIdx.x;
    const int w = tid >> 6, l = tid & 63;
    if (tid < Hn) tv[tid] = tvec[s * Hn + tid];
    const int j4 = (l & 15) * 4;
    f4_t xq = *(const f4_t*)&xprice[s * Hn + j4];
    __syncthreads();

    const float* Wbs = Wb + (size_t)s * Hn * Hn * Hn;
    for (int g = 0; g < 256; ++g) {
        int P = w * 1024 + g * 4 + (l >> 4);      // pair id = k*64 + i
        f4_t wv = *(const f4_t*)&Wbs[(size_t)P * Hn + j4];
        float dp = wv[0] * xq[0] + wv[1] * xq[1] + wv[2] * xq[2] + wv[3] * xq[3];
        dp += __shfl_xor(dp, 8);
        dp += __shfl_xor(dp, 4);
        dp += __shfl_xor(dp, 2);
        dp += __shfl_xor(dp, 1);
        if ((l & 15) == 0) { int k = P >> 6, i = P & 63; uT[i][k] = dp; }
    }
    __syncthreads();
    if (tid < Hn) {
        const int k = tid;
        float a = bb[s * Hn + k];
        for (int i = 0; i < Hn; i++) a += tv[i] * uT[i][k];
        float c = tanhf_(a);
        cl[k] = c; combined[s * Hn + k] = c;
    }
    __syncthreads();
    if (tid < Hn) {
        const int j = tid;
        float aq = bq[j], ak = bk[j];
        for (int i = 0; i < Hn; i++) { float ci = cl[i]; aq += ci * Wq[i * Hn + j]; ak += ci * Wk[i * Hn + j]; }
        qg[s * Hn + j] = aq; kg[s * Hn + j] = ak;
    }
    if (tid >= Hn && tid < Hn + 2) {
        const int c = tid - Hn;
        float a = bbl[s * 2 + c];
        for (int i = 0; i < Hn; i++) a += cl[i] * Wbl[(size_t)s * Hn * 2 + i * 2 + c];
        out1[s * 2 + c] = tanhf_(a);
    }
}

// ---------------------------------------------------------------------------
// Cross-stock MHSA (4 heads, dh=16, v=identity) + elu head + blend + softmax.
// One block per query stock. Writes d_out[1 + 2*sq .. ].
// ---------------------------------------------------------------------------
__global__ __launch_bounds__(256) void mhsa(
    const float* __restrict__ qg, const float* __restrict__ kg,
    const float* __restrict__ combined, const float* __restrict__ Wf,
    const float* __restrict__ bfp, const float* __restrict__ out1,
    float* __restrict__ dout)
{
    __shared__ __align__(16) float ql[Hn];
    __shared__ float sl[NHn][Sn];
    __shared__ float hsum[NHn];
    __shared__ float ao[Hn];
    __shared__ float red2[8];

    const int sq = blockIdx.x, tid = threadIdx.x;
    if (tid < Hn) ql[tid] = qg[sq * Hn + tid];
    __syncthreads();

    for (int id = tid; id < Sn * NHn; id += 256) {
        int t = id >> 2, h = id & 3;
        const float* kp = &kg[t * Hn + h * 16];
        float a = 0.f;
        #pragma unroll
        for (int x = 0; x < 16; x += 4) {
            f4_t kv = *(const f4_t*)&kp[x];
            f4_t qv = *(const f4_t*)&ql[h * 16 + x];
            a += kv[0] * qv[0] + kv[1] * qv[1] + kv[2] * qv[2] + kv[3] * qv[3];
        }
        sl[h][t] = a * 0.25f;
    }
    __syncthreads();
    for (int h = 0; h < NHn; ++h) {
        float m = -1e30f;
        for (int t = tid; t < Sn; t += 256) m = fmaxf(m, sl[h][t]);
        for (int o = 32; o; o >>= 1) m = fmaxf(m, __shfl_xor(m, o));
        if ((tid & 63) == 0) red2[tid >> 6] = m;
        __syncthreads();
        m = fmaxf(fmaxf(red2[0], red2[1]), fmaxf(red2[2], red2[3]));
        float ps = 0.f;
        for (int t = tid; t < Sn; t += 256) { float p = __expf(sl[h][t] - m); sl[h][t] = p; ps += p; }
        for (int o = 32; o; o >>= 1) ps += __shfl_xor(ps, o);
        if ((tid & 63) == 0) red2[4 + (tid >> 6)] = ps;
        __syncthreads();
        if (tid == 0) hsum[h] = red2[4] + red2[5] + red2[6] + red2[7];
        __syncthreads();
    }
    if (tid < Hn) {
        const int j = tid, h = j >> 4;
        float a = 0.f;
        for (int t = 0; t < Sn; t++) a += sl[h][t] * combined[t * Hn + j];
        ao[j] = a / hsum[h];
    }
    __syncthreads();
    if (tid == 0) {
        float l0 = bfp[0], l1 = bfp[1];
        for (int j = 0; j < Hn; j++) { float v = ao[j]; l0 += v * Wf[j * 2]; l1 += v * Wf[j * 2 + 1]; }
        l0 = l0 > 0.f ? l0 : __expf(l0) - 1.f;   // elu
        l1 = l1 > 0.f ? l1 : __expf(l1) - 1.f;
        l0 += out1[sq * 2]; l1 += out1[sq * 2 + 1];
        float m = fmaxf(l0, l1);
        float e0 = __expf(l0 - m), e1 = __expf(l1 - m);
        float inv = 1.f / (e0 + e1);
        dout[1 + sq * 2] = e0 * inv;
        dout[2 + sq * 2] = e1 * inv;
    }
}

// ---------------------------------------------------------------------------
// Loss: -mean(log_softmax(output)[arange, label]); output already in d_out.
// ---------------------------------------------------------------------------
__global__ __launch_bounds__(512) void loss_k(float* __restrict__ dout,
                                              const int* __restrict__ label)
{
    __shared__ float red[512];
    const int tid = threadIdx.x;
    float a = 0.f;
    if (tid < Sn) {
        float p0 = dout[1 + 2 * tid], p1 = dout[2 + 2 * tid];
        float m = fmaxf(p0, p1);
        float lse = m + __logf(__expf(p0 - m) + __expf(p1 - m));
        float pl = label[tid] ? p1 : p0;
        a = -(pl - lse);
    }
    red[tid] = a;
    __syncthreads();
    for (int o = 256; o; o >>= 1) {
        if (tid < o) red[tid] += red[tid + o];
        __syncthreads();
    }
    if (tid == 0) dout[0] = red[0] / (float)Sn;
}

extern "C" void kernel_launch(void* const* d_in, const int* in_sizes, int n_in,
                              void* d_out, int out_size, void* d_ws, size_t ws_size,
                              hipStream_t stream)
{
    const float* text  = (const float*)d_in[0];
    const float* price = (const float*)d_in[1];
    const int*   label = (const int*)  d_in[2];
    const float* Wih_p = (const float*)d_in[5];
    const float* Whh_p = (const float*)d_in[6];
    const float* bih_p = (const float*)d_in[7];
    const float* bhh_p = (const float*)d_in[8];
    const float* Wa_p  = (const float*)d_in[9];
    const float* va_p  = (const float*)d_in[10];
    const float* Wih_t = (const float*)d_in[11];
    const float* Whh_t = (const float*)d_in[12];
    const float* bih_t = (const float*)d_in[13];
    const float* bhh_t = (const float*)d_in[14];
    const float* Wa_t  = (const float*)d_in[15];
    const float* va_t  = (const float*)d_in[16];
    const float* Wih_s = (const float*)d_in[17];
    const float* Whh_s = (const float*)d_in[18];
    const float* bih_s = (const float*)d_in[19];
    const float* bhh_s = (const float*)d_in[20];
    const float* Wa_s  = (const float*)d_in[21];
    const float* va_s  = (const float*)d_in[22];
    const float* Wb    = (const float*)d_in[23];
    const float* bb    = (const float*)d_in[24];
    const float* Wbl   = (const float*)d_in[25];
    const float* bbl   = (const float*)d_in[26];
    const float* Wq    = (const float*)d_in[27];
    const float* bq    = (const float*)d_in[28];
    const float* Wk    = (const float*)d_in[29];
    const float* bk    = (const float*)d_in[30];
    const float* Wf    = (const float*)d_in[31];
    const float* bf_   = (const float*)d_in[32];

    float* ws = (float*)d_ws;
    float* news     = ws;              // 320000
    float* xprice   = ws + 320000;     // 32000
    float* tvec     = ws + 352000;     // 32000
    float* combined = ws + 384000;     // 32000
    float* qg       = ws + 416000;     // 32000
    float* kg       = ws + 448000;     // 32000
    float* out1     = ws + 480000;     // 1000
    float* dout = (float*)d_out;

    text_enc<<<Sn * Dn, 256, 0, stream>>>(text, Wih_t, Whh_t, bih_t, bhh_t, Wa_t, va_t, news);
    small_gru<FPn><<<Sn, 192, 0, stream>>>(price, Wih_p, Whh_p, bih_p, bhh_p, Wa_p, va_p, xprice);
    small_gru<Hn><<<Sn, 192, 0, stream>>>(news, Wih_s, Whh_s, bih_s, bhh_s, Wa_s, va_s, tvec);
    bilinear_head<<<Sn, 256, 0, stream>>>(Wb, bb, Wbl, bbl, Wq, bq, Wk, bk,
                                          xprice, tvec, combined, qg, kg, out1);
    mhsa<<<Sn, 256, 0, stream>>>(qg, kg, combined, Wf, bf_, out1, dout);
    loss_k<<<1, 512, 0, stream>>>(dout, label);
}

// Round 2
// 772.731 us; speedup vs baseline: 1.8047x; 1.8047x over previous
//
#include <hip/hip_runtime.h>

#define Sn 500
#define Dn 10
#define Tn 40
#define FPn 3
#define FTn 512
#define Hn 64
#define G3 192
#define NHn 4

typedef __attribute__((ext_vector_type(8))) short bf8_t;   // 8 x bf16 bits
typedef __attribute__((ext_vector_type(4))) float f4_t;

__device__ __forceinline__ unsigned short f2bf(float f) {
    union { float f; unsigned int u; } v; v.f = f;
    unsigned int r = v.u + 0x7fffu + ((v.u >> 16) & 1u);   // round-to-nearest-even
    return (unsigned short)(r >> 16);
}
__device__ __forceinline__ float bflo(unsigned int u) {
    union { unsigned int u; float f; } v; v.u = u << 16; return v.f;
}
__device__ __forceinline__ float bfhi(unsigned int u) {
    union { unsigned int u; float f; } v; v.u = u & 0xffff0000u; return v.f;
}
__device__ __forceinline__ unsigned int cvtpk(float lo, float hi) {
    unsigned int r;
    asm("v_cvt_pk_bf16_f32 %0, %1, %2" : "=v"(r) : "v"(lo), "v"(hi));
    return r;
}
__device__ __forceinline__ float sigmoidf_(float x) { return 1.f / (1.f + __expf(-x)); }
__device__ __forceinline__ float tanhf_(float x) {
    x = fminf(15.f, fmaxf(-15.f, x));
    float e = __expf(2.f * x);
    return (e - 1.f) / (e + 1.f);
}
__device__ __forceinline__ float dot8(uint4 wv, f4_t hA, f4_t hB) {
    return bflo(wv.x) * hA[0] + bfhi(wv.x) * hA[1]
         + bflo(wv.y) * hA[2] + bfhi(wv.y) * hA[3]
         + bflo(wv.z) * hB[0] + bfhi(wv.z) * hB[1]
         + bflo(wv.w) * hB[2] + bfhi(wv.w) * hB[3];
}
union bfu { bf8_t v; unsigned int u[4]; };

// ---------------------------------------------------------------------------
// Kernel A: gi = x @ Wih_t + bih_t for all 5000 sequences, batched MFMA GEMM.
// Per stock: (400 x 512) @ (512 x 192). Block = 4 waves; block owns an 80-row
// m-chunk; wave w owns a 48-col n-strip (3 n-tiles), 5 m-tiles each.
// ---------------------------------------------------------------------------
__global__ __launch_bounds__(256) void gi_gemm(
    const float* __restrict__ text, const float* __restrict__ Wih,
    const float* __restrict__ bih, float* __restrict__ gi)
{
    __shared__ __align__(16) float As[80][36];   // +4 pad: conflict-free frag reads

    const int blk = blockIdx.x;
    const int s = blk / 5, mb = (blk % 5) * 80;
    const int tid = threadIdx.x, w = tid >> 6, lane = tid & 63;
    const int rt = lane & 15, kg = lane >> 4;

    const float* Wihs = Wih + (size_t)s * FTn * G3;
    const float* xrow = text + ((size_t)s * 400 + mb) * FTn;

    f4_t acc[5][3];
    #pragma unroll
    for (int a = 0; a < 5; a++)
        #pragma unroll
        for (int b = 0; b < 3; b++) acc[a][b] = (f4_t){0.f, 0.f, 0.f, 0.f};

    for (int kk = 0; kk < FTn / 32; ++kk) {
        // stage 80x32 f32 A-slice, coalesced
        for (int e = tid; e < 640; e += 256) {
            int r = e >> 3, c4 = (e & 7) * 4;
            *(f4_t*)&As[r][c4] = *(const f4_t*)(xrow + (size_t)r * FTn + kk * 32 + c4);
        }
        __syncthreads();

        // B fragments (3 n-tiles), from global (L2/L3-resident across blocks)
        bfu bfr[3];
        #pragma unroll
        for (int nc = 0; nc < 3; ++nc) {
            const int col = w * 48 + nc * 16 + rt;
            const float* bp = Wihs + (size_t)(kk * 32 + kg * 8) * G3 + col;
            float b0 = bp[0], b1 = bp[G3], b2 = bp[2 * G3], b3 = bp[3 * G3];
            float b4 = bp[4 * G3], b5 = bp[5 * G3], b6 = bp[6 * G3], b7 = bp[7 * G3];
            bfr[nc].u[0] = cvtpk(b0, b1); bfr[nc].u[1] = cvtpk(b2, b3);
            bfr[nc].u[2] = cvtpk(b4, b5); bfr[nc].u[3] = cvtpk(b6, b7);
        }
        // A fragments + MFMA
        #pragma unroll
        for (int mt = 0; mt < 5; ++mt) {
            const float* ap = &As[mt * 16 + rt][kg * 8];
            f4_t a0 = *(const f4_t*)ap, a1 = *(const f4_t*)(ap + 4);
            bfu af;
            af.u[0] = cvtpk(a0[0], a0[1]); af.u[1] = cvtpk(a0[2], a0[3]);
            af.u[2] = cvtpk(a1[0], a1[1]); af.u[3] = cvtpk(a1[2], a1[3]);
            #pragma unroll
            for (int nc = 0; nc < 3; ++nc)
                acc[mt][nc] = __builtin_amdgcn_mfma_f32_16x16x32_bf16(af.v, bfr[nc].v, acc[mt][nc], 0, 0, 0);
        }
        __syncthreads();
    }

    const float* bihs = bih + (size_t)s * G3;
    #pragma unroll
    for (int nc = 0; nc < 3; ++nc) {
        const int col = w * 48 + nc * 16 + rt;
        const float bv = bihs[col];
        #pragma unroll
        for (int mt = 0; mt < 5; ++mt)
            #pragma unroll
            for (int rg = 0; rg < 4; rg++) {
                int row = mb + mt * 16 + kg * 4 + rg;
                gi[((size_t)s * 400 + row) * G3 + col] = acc[mt][nc][rg] + bv;
            }
    }
}

// ---------------------------------------------------------------------------
// Kernel B: text GRU recurrence + fused online-softmax attention pooling.
// One block per stock, 10 waves; wave d runs day d's 40-step chain with NO
// block barriers (wave-synchronous LDS). Whh^T and Wa^T staged bf16 with
// conflict-free XOR swizzle. Lane c owns hidden unit c (gates r,z,n = rows
// c, c+64, c+128 of Whh^T).
// ---------------------------------------------------------------------------
__global__ __launch_bounds__(640) void gru_text(
    const float* __restrict__ gi, const float* __restrict__ Whh,
    const float* __restrict__ bhh, const float* __restrict__ Wa,
    const float* __restrict__ va, float* __restrict__ news)
{
    __shared__ __align__(16) unsigned char whh[G3 * 128];   // bf16 [j][i], swizzled
    __shared__ __align__(16) unsigned char waT[Hn * 128];   // bf16 [k][i], swizzled
    __shared__ __align__(16) float hcurL[Dn][Hn];

    const int s = blockIdx.x, tid = threadIdx.x;
    const int w = tid >> 6, c = tid & 63;

    const float* Whhs = Whh + (size_t)s * Hn * G3;
    for (int e = tid; e < Hn * G3; e += 640) {
        int i = e / G3, j = e - i * G3;
        *(unsigned short*)(whh + j * 128 + ((2 * i) ^ ((j & 7) << 4))) = f2bf(Whhs[e]);
    }
    const float* Was = Wa + (size_t)s * Hn * Hn;
    for (int e = tid; e < Hn * Hn; e += 640) {
        int i = e >> 6, k = e & 63;
        *(unsigned short*)(waT + k * 128 + ((2 * i) ^ ((k & 7) << 4))) = f2bf(Was[e]);
    }
    hcurL[w][c] = 0.f;
    const float vak = va[(size_t)s * Hn + c];
    const float bh0 = bhh[(size_t)s * G3 + c];
    const float bh1 = bhh[(size_t)s * G3 + 64 + c];
    const float bh2 = bhh[(size_t)s * G3 + 128 + c];
    __syncthreads();

    const float* gseq = gi + ((size_t)s * 400 + w * 40) * G3;
    const int sw = (c & 7) << 4;
    float h = 0.f, accv = 0.f, den = 0.f, m = -1e30f;
    float g0 = gseq[c], g1 = gseq[64 + c], g2 = gseq[128 + c];

    for (int t = 0; t < Tn; ++t) {
        // prefetch next step's gi (hidden under the matvec)
        float n0 = 0.f, n1 = 0.f, n2 = 0.f;
        if (t < Tn - 1) {
            const float* gn = gseq + (t + 1) * G3;
            n0 = gn[c]; n1 = gn[64 + c]; n2 = gn[128 + c];
        }
        // gh = h @ Whh + bhh for this lane's three gate rows
        float a0 = bh0, a1 = bh1, a2 = bh2;
        #pragma unroll
        for (int ic = 0; ic < 8; ++ic) {
            const int off = (ic * 16) ^ sw;
            uint4 w0 = *(const uint4*)(whh + c * 128 + off);
            uint4 w1 = *(const uint4*)(whh + (c + 64) * 128 + off);
            uint4 w2 = *(const uint4*)(whh + (c + 128) * 128 + off);
            f4_t hA = *(const f4_t*)&hcurL[w][ic * 8];
            f4_t hB = *(const f4_t*)&hcurL[w][ic * 8 + 4];
            a0 += dot8(w0, hA, hB);
            a1 += dot8(w1, hA, hB);
            a2 += dot8(w2, hA, hB);
        }
        float r = sigmoidf_(g0 + a0);
        float z = sigmoidf_(g1 + a1);
        float n = tanhf_(g2 + r * a2);
        h = (1.f - z) * n + z * h;

        __builtin_amdgcn_wave_barrier();
        hcurL[w][c] = h;
        __builtin_amdgcn_wave_barrier();

        // score_t = sum_k tanh(h . Wa[:,k]) * va[k]  (lane k computes column k)
        float sk = 0.f;
        #pragma unroll
        for (int ic = 0; ic < 8; ++ic) {
            const int off = (ic * 16) ^ sw;
            uint4 wv = *(const uint4*)(waT + c * 128 + off);
            f4_t hA = *(const f4_t*)&hcurL[w][ic * 8];
            f4_t hB = *(const f4_t*)&hcurL[w][ic * 8 + 4];
            sk += dot8(wv, hA, hB);
        }
        float term = tanhf_(sk) * vak;
        #pragma unroll
        for (int off = 32; off; off >>= 1) term += __shfl_xor(term, off);

        // online softmax accumulation of alpha[t] * h
        float mn = fmaxf(m, term);
        float scale = __expf(m - mn);
        float p = __expf(term - mn);
        den = den * scale + p;
        accv = accv * scale + p * h;
        m = mn;

        g0 = n0; g1 = n1; g2 = n2;
    }
    news[((size_t)s * Dn + w) * Hn + c] = accv / den;
}

// ---------------------------------------------------------------------------
// FALLBACK (round-1) text encoder: used only if workspace is too small.
// ---------------------------------------------------------------------------
__global__ __launch_bounds__(256) void text_enc(
    const float* __restrict__ text, const float* __restrict__ Wih,
    const float* __restrict__ Whh, const float* __restrict__ bih,
    const float* __restrict__ bhh, const float* __restrict__ Wa,
    const float* __restrict__ va, float* __restrict__ news)
{
    __shared__ __align__(16) float gi[Tn][G3];
    __shared__ __align__(16) unsigned char whhT[G3 * Hn * 2];
    __shared__ __align__(16) float hs[Tn][Hn];
    __shared__ __align__(16) float hcur[Hn];
    __shared__ float gh[G3];
    __shared__ float red[160];
    __shared__ float scb[Tn], alb[Tn];
    __shared__ float ssum;

    const int blk = blockIdx.x;
    const int s = blk / Dn;
    const int tid = threadIdx.x;
    const int lane = tid & 63, w = tid >> 6;

    const float* Wihs = Wih + (size_t)s * FTn * G3;
    const float* Whhs = Whh + (size_t)s * Hn * G3;
    const float* xblk = text + (size_t)blk * Tn * FTn;

    for (int e = tid; e < Hn * G3; e += 256) {
        int i = e / G3, j = e - i * G3;
        *(unsigned short*)(whhT + j * 128 + (((i * 2) ^ ((j & 7) << 4)))) = f2bf(Whhs[e]);
    }
    if (tid < Hn) hcur[tid] = 0.f;

    f4_t acc[3][3];
    #pragma unroll
    for (int a = 0; a < 3; a++)
        #pragma unroll
        for (int b = 0; b < 3; b++) acc[a][b] = (f4_t){0.f, 0.f, 0.f, 0.f};
    const int rt = lane & 15, kg = lane >> 4;
    for (int kk = 0; kk < FTn / 32; ++kk) {
        const int kbase = kk * 32 + kg * 8;
        bf8_t afr[3], bfr[3];
        #pragma unroll
        for (int mt = 0; mt < 3; ++mt) {
            int r = mt * 16 + rt;
            if (r < Tn) {
                const float* p = xblk + r * FTn + kbase;
                f4_t v0 = *(const f4_t*)p, v1 = *(const f4_t*)(p + 4);
                afr[mt][0] = (short)f2bf(v0[0]); afr[mt][1] = (short)f2bf(v0[1]);
                afr[mt][2] = (short)f2bf(v0[2]); afr[mt][3] = (short)f2bf(v0[3]);
                afr[mt][4] = (short)f2bf(v1[0]); afr[mt][5] = (short)f2bf(v1[1]);
                afr[mt][6] = (short)f2bf(v1[2]); afr[mt][7] = (short)f2bf(v1[3]);
            } else {
                #pragma unroll
                for (int b = 0; b < 8; b++) afr[mt][b] = 0;
            }
        }
        #pragma unroll
        for (int nc = 0; nc < 3; ++nc) {
            const int col = (w * 3 + nc) * 16 + rt;
            const float* bp = Wihs + (size_t)kbase * G3 + col;
            #pragma unroll
            for (int b = 0; b < 8; b++) bfr[nc][b] = (short)f2bf(bp[b * G3]);
        }
        #pragma unroll
        for (int mt = 0; mt < 3; ++mt)
            #pragma unroll
            for (int nc = 0; nc < 3; ++nc)
                acc[mt][nc] = __builtin_amdgcn_mfma_f32_16x16x32_bf16(afr[mt], bfr[nc], acc[mt][nc], 0, 0, 0);
    }
    const float* bihs = bih + (size_t)s * G3;
    #pragma unroll
    for (int nc = 0; nc < 3; ++nc) {
        const int col = (w * 3 + nc) * 16 + rt;
        const float bv = bihs[col];
        #pragma unroll
        for (int mt = 0; mt < 3; ++mt) {
            #pragma unroll
            for (int rg = 0; rg < 4; rg++) {
                int r = mt * 16 + kg * 4 + rg;
                if (r < Tn) gi[r][col] = acc[mt][nc][rg] + bv;
            }
        }
    }
    __syncthreads();

    const float* bhhs = bhh + (size_t)s * G3;
    for (int t = 0; t < Tn; t++) {
        if (tid < G3) {
            const int j = tid;
            const int sw = (j & 7) << 4;
            float a = bhhs[j];
            #pragma unroll
            for (int ic = 0; ic < 8; ++ic) {
                uint4 wv = *(const uint4*)(whhT + j * 128 + ((ic * 16) ^ sw));
                f4_t h0 = *(const f4_t*)&hcur[ic * 8];
                f4_t h1 = *(const f4_t*)&hcur[ic * 8 + 4];
                a += bflo(wv.x) * h0[0] + bfhi(wv.x) * h0[1]
                   + bflo(wv.y) * h0[2] + bfhi(wv.y) * h0[3]
                   + bflo(wv.z) * h1[0] + bfhi(wv.z) * h1[1]
                   + bflo(wv.w) * h1[2] + bfhi(wv.w) * h1[3];
            }
            gh[j] = a;
        }
        __syncthreads();
        if (tid < Hn) {
            const int c = tid;
            float r = sigmoidf_(gi[t][c] + gh[c]);
            float z = sigmoidf_(gi[t][Hn + c] + gh[Hn + c]);
            float n = tanhf_(gi[t][2 * Hn + c] + r * gh[2 * Hn + c]);
            float hn = (1.f - z) * n + z * hcur[c];
            hcur[c] = hn;
            hs[t][c] = hn;
        }
        __syncthreads();
    }

    const float* Was = Wa + (size_t)s * Hn * Hn;
    const float* vas = va + (size_t)s * Hn;
    if (tid < 160) {
        const int t = tid % Tn, q = tid / Tn;
        float part = 0.f;
        for (int k = q * 16; k < q * 16 + 16; ++k) {
            float dot = 0.f;
            #pragma unroll 4
            for (int i = 0; i < Hn; i += 4) {
                f4_t hv = *(const f4_t*)&hs[t][i];
                dot += hv[0] * Was[i * Hn + k] + hv[1] * Was[(i + 1) * Hn + k]
                     + hv[2] * Was[(i + 2) * Hn + k] + hv[3] * Was[(i + 3) * Hn + k];
            }
            part += tanhf_(dot) * vas[k];
        }
        red[tid] = part;
    }
    __syncthreads();
    if (tid < Tn) scb[tid] = red[tid] + red[Tn + tid] + red[2 * Tn + tid] + red[3 * Tn + tid];
    __syncthreads();
    if (tid == 0) {
        float m = -1e30f;
        for (int t = 0; t < Tn; t++) m = fmaxf(m, scb[t]);
        float ss = 0.f;
        for (int t = 0; t < Tn; t++) { float p = __expf(scb[t] - m); alb[t] = p; ss += p; }
        ssum = ss;
    }
    __syncthreads();
    if (tid < Hn) {
        float o = 0.f;
        for (int t = 0; t < Tn; t++) o += alb[t] * hs[t][tid];
        news[(size_t)blk * Hn + tid] = o / ssum;
    }
}

// ---------------------------------------------------------------------------
// Small GRU (price: FIN=3, day-sequence: FIN=64) over D=10 steps + attn pool.
// ---------------------------------------------------------------------------
template<int FIN>
__global__ __launch_bounds__(192) void small_gru(
    const float* __restrict__ xin, const float* __restrict__ Wih,
    const float* __restrict__ Whh, const float* __restrict__ bih,
    const float* __restrict__ bhh, const float* __restrict__ Wa,
    const float* __restrict__ va, float* __restrict__ outv)
{
    __shared__ __align__(16) float whhT[G3 * Hn];
    __shared__ float gi[Dn][G3];
    __shared__ float xs[Dn * FIN];
    __shared__ __align__(16) float hs[Dn][Hn];
    __shared__ __align__(16) float hcur[Hn];
    __shared__ float gh[G3];
    __shared__ float red[160];
    __shared__ float scb[Dn], alb[Dn];
    __shared__ float ssum;

    const int s = blockIdx.x, tid = threadIdx.x;
    char* wb = (char*)whhT;

    for (int e = tid; e < Dn * FIN; e += 192) xs[e] = xin[(size_t)s * Dn * FIN + e];
    const float* Whhs = Whh + (size_t)s * Hn * G3;
    for (int e = tid; e < Hn * G3; e += 192) {
        int i = e / G3, j = e - i * G3;
        *(float*)(wb + j * 256 + (((i * 4) ^ ((j & 15) << 4)))) = Whhs[e];
    }
    if (tid < Hn) hcur[tid] = 0.f;
    __syncthreads();

    {
        const int j = tid;
        const float* Wihs = Wih + (size_t)s * FIN * G3;
        const float bi = bih[(size_t)s * G3 + j];
        for (int t = 0; t < Dn; t++) {
            float a = bi;
            for (int i = 0; i < FIN; i++) a += xs[t * FIN + i] * Wihs[i * G3 + j];
            gi[t][j] = a;
        }
    }
    __syncthreads();

    const float* bhhs = bhh + (size_t)s * G3;
    for (int t = 0; t < Dn; t++) {
        {
            const int j = tid;
            const int sw = (j & 15) << 4;
            float a = bhhs[j];
            #pragma unroll
            for (int ic = 0; ic < 16; ++ic) {
                f4_t wv = *(const f4_t*)(wb + j * 256 + ((ic * 16) ^ sw));
                f4_t hv = *(const f4_t*)&hcur[ic * 4];
                a += wv[0] * hv[0] + wv[1] * hv[1] + wv[2] * hv[2] + wv[3] * hv[3];
            }
            gh[j] = a;
        }
        __syncthreads();
        if (tid < Hn) {
            const int c = tid;
            float r = sigmoidf_(gi[t][c] + gh[c]);
            float z = sigmoidf_(gi[t][Hn + c] + gh[Hn + c]);
            float n = tanhf_(gi[t][2 * Hn + c] + r * gh[2 * Hn + c]);
            float hn = (1.f - z) * n + z * hcur[c];
            hcur[c] = hn; hs[t][c] = hn;
        }
        __syncthreads();
    }

    const float* Was = Wa + (size_t)s * Hn * Hn;
    const float* vas = va + (size_t)s * Hn;
    if (tid < Dn * 16) {
        const int t = tid >> 4, kc = tid & 15;
        float part = 0.f;
        for (int k = kc * 4; k < kc * 4 + 4; ++k) {
            float dot = 0.f;
            for (int i = 0; i < Hn; i += 4) {
                f4_t hv = *(const f4_t*)&hs[t][i];
                dot += hv[0] * Was[i * Hn + k] + hv[1] * Was[(i + 1) * Hn + k]
                     + hv[2] * Was[(i + 2) * Hn + k] + hv[3] * Was[(i + 3) * Hn + k];
            }
            part += tanhf_(dot) * vas[k];
        }
        red[tid] = part;
    }
    __syncthreads();
    if (tid < Dn) {
        float sc = 0.f;
        for (int kc = 0; kc < 16; kc++) sc += red[tid * 16 + kc];
        scb[tid] = sc;
    }
    __syncthreads();
    if (tid == 0) {
        float m = -1e30f;
        for (int t = 0; t < Dn; t++) m = fmaxf(m, scb[t]);
        float ss = 0.f;
        for (int t = 0; t < Dn; t++) { float p = __expf(scb[t] - m); alb[t] = p; ss += p; }
        ssum = ss;
    }
    __syncthreads();
    if (tid < Hn) {
        float o = 0.f;
        for (int t = 0; t < Dn; t++) o += alb[t] * hs[t][tid];
        outv[(size_t)s * Hn + tid] = o / ssum;
    }
}

// ---------------------------------------------------------------------------
// Bilinear fusion + per-stock q/k projections + blend head. One block/stock.
// ---------------------------------------------------------------------------
__global__ __launch_bounds__(256) void bilinear_head(
    const float* __restrict__ Wb, const float* __restrict__ bb,
    const float* __restrict__ Wbl, const float* __restrict__ bbl,
    const float* __restrict__ Wq, const float* __restrict__ bq,
    const float* __restrict__ Wk, const float* __restrict__ bk,
    const float* __restrict__ xprice, const float* __restrict__ tvec,
    float* __restrict__ combined, float* __restrict__ qg,
    float* __restrict__ kg, float* __restrict__ out1)
{
    __shared__ __align__(16) float uT[Hn][Hn];
    __shared__ float cl[Hn];
    __shared__ float tv[Hn];

    const int s = blockIdx.x, tid = threadIdx.x;
    const int w = tid >> 6, l = tid & 63;
    if (tid < Hn) tv[tid] = tvec[s * Hn + tid];
    const int j4 = (l & 15) * 4;
    f4_t xq = *(const f4_t*)&xprice[s * Hn + j4];
    __syncthreads();

    const float* Wbs = Wb + (size_t)s * Hn * Hn * Hn;
    for (int g = 0; g < 256; ++g) {
        int P = w * 1024 + g * 4 + (l >> 4);
        f4_t wv = *(const f4_t*)&Wbs[(size_t)P * Hn + j4];
        float dp = wv[0] * xq[0] + wv[1] * xq[1] + wv[2] * xq[2] + wv[3] * xq[3];
        dp += __shfl_xor(dp, 8);
        dp += __shfl_xor(dp, 4);
        dp += __shfl_xor(dp, 2);
        dp += __shfl_xor(dp, 1);
        if ((l & 15) == 0) { int k = P >> 6, i = P & 63; uT[i][k] = dp; }
    }
    __syncthreads();
    if (tid < Hn) {
        const int k = tid;
        float a = bb[s * Hn + k];
        for (int i = 0; i < Hn; i++) a += tv[i] * uT[i][k];
        float c = tanhf_(a);
        cl[k] = c; combined[s * Hn + k] = c;
    }
    __syncthreads();
    if (tid < Hn) {
        const int j = tid;
        float aq = bq[j], ak = bk[j];
        for (int i = 0; i < Hn; i++) { float ci = cl[i]; aq += ci * Wq[i * Hn + j]; ak += ci * Wk[i * Hn + j]; }
        qg[s * Hn + j] = aq; kg[s * Hn + j] = ak;
    }
    if (tid >= Hn && tid < Hn + 2) {
        const int c = tid - Hn;
        float a = bbl[s * 2 + c];
        for (int i = 0; i < Hn; i++) a += cl[i] * Wbl[(size_t)s * Hn * 2 + i * 2 + c];
        out1[s * 2 + c] = tanhf_(a);
    }
}

// ---------------------------------------------------------------------------
// Cross-stock MHSA + elu head + blend + softmax.
// ---------------------------------------------------------------------------
__global__ __launch_bounds__(256) void mhsa(
    const float* __restrict__ qg, const float* __restrict__ kg,
    const float* __restrict__ combined, const float* __restrict__ Wf,
    const float* __restrict__ bfp, const float* __restrict__ out1,
    float* __restrict__ dout)
{
    __shared__ __align__(16) float ql[Hn];
    __shared__ float sl[NHn][Sn];
    __shared__ float hsum[NHn];
    __shared__ float ao[Hn];
    __shared__ float red2[8];

    const int sq = blockIdx.x, tid = threadIdx.x;
    if (tid < Hn) ql[tid] = qg[sq * Hn + tid];
    __syncthreads();

    for (int id = tid; id < Sn * NHn; id += 256) {
        int t = id >> 2, h = id & 3;
        const float* kp = &kg[t * Hn + h * 16];
        float a = 0.f;
        #pragma unroll
        for (int x = 0; x < 16; x += 4) {
            f4_t kv = *(const f4_t*)&kp[x];
            f4_t qv = *(const f4_t*)&ql[h * 16 + x];
            a += kv[0] * qv[0] + kv[1] * qv[1] + kv[2] * qv[2] + kv[3] * qv[3];
        }
        sl[h][t] = a * 0.25f;
    }
    __syncthreads();
    for (int h = 0; h < NHn; ++h) {
        float m = -1e30f;
        for (int t = tid; t < Sn; t += 256) m = fmaxf(m, sl[h][t]);
        for (int o = 32; o; o >>= 1) m = fmaxf(m, __shfl_xor(m, o));
        if ((tid & 63) == 0) red2[tid >> 6] = m;
        __syncthreads();
        m = fmaxf(fmaxf(red2[0], red2[1]), fmaxf(red2[2], red2[3]));
        float ps = 0.f;
        for (int t = tid; t < Sn; t += 256) { float p = __expf(sl[h][t] - m); sl[h][t] = p; ps += p; }
        for (int o = 32; o; o >>= 1) ps += __shfl_xor(ps, o);
        if ((tid & 63) == 0) red2[4 + (tid >> 6)] = ps;
        __syncthreads();
        if (tid == 0) hsum[h] = red2[4] + red2[5] + red2[6] + red2[7];
        __syncthreads();
    }
    if (tid < Hn) {
        const int j = tid, h = j >> 4;
        float a = 0.f;
        for (int t = 0; t < Sn; t++) a += sl[h][t] * combined[t * Hn + j];
        ao[j] = a / hsum[h];
    }
    __syncthreads();
    if (tid == 0) {
        float l0 = bfp[0], l1 = bfp[1];
        for (int j = 0; j < Hn; j++) { float v = ao[j]; l0 += v * Wf[j * 2]; l1 += v * Wf[j * 2 + 1]; }
        l0 = l0 > 0.f ? l0 : __expf(l0) - 1.f;
        l1 = l1 > 0.f ? l1 : __expf(l1) - 1.f;
        l0 += out1[sq * 2]; l1 += out1[sq * 2 + 1];
        float m = fmaxf(l0, l1);
        float e0 = __expf(l0 - m), e1 = __expf(l1 - m);
        float inv = 1.f / (e0 + e1);
        dout[1 + sq * 2] = e0 * inv;
        dout[2 + sq * 2] = e1 * inv;
    }
}

__global__ __launch_bounds__(512) void loss_k(float* __restrict__ dout,
                                              const int* __restrict__ label)
{
    __shared__ float red[512];
    const int tid = threadIdx.x;
    float a = 0.f;
    if (tid < Sn) {
        float p0 = dout[1 + 2 * tid], p1 = dout[2 + 2 * tid];
        float m = fmaxf(p0, p1);
        float lse = m + __logf(__expf(p0 - m) + __expf(p1 - m));
        float pl = label[tid] ? p1 : p0;
        a = -(pl - lse);
    }
    red[tid] = a;
    __syncthreads();
    for (int o = 256; o; o >>= 1) {
        if (tid < o) red[tid] += red[tid + o];
        __syncthreads();
    }
    if (tid == 0) dout[0] = red[0] / (float)Sn;
}

extern "C" void kernel_launch(void* const* d_in, const int* in_sizes, int n_in,
                              void* d_out, int out_size, void* d_ws, size_t ws_size,
                              hipStream_t stream)
{
    const float* text  = (const float*)d_in[0];
    const float* price = (const float*)d_in[1];
    const int*   label = (const int*)  d_in[2];
    const float* Wih_p = (const float*)d_in[5];
    const float* Whh_p = (const float*)d_in[6];
    const float* bih_p = (const float*)d_in[7];
    const float* bhh_p = (const float*)d_in[8];
    const float* Wa_p  = (const float*)d_in[9];
    const float* va_p  = (const float*)d_in[10];
    const float* Wih_t = (const float*)d_in[11];
    const float* Whh_t = (const float*)d_in[12];
    const float* bih_t = (const float*)d_in[13];
    const float* bhh_t = (const float*)d_in[14];
    const float* Wa_t  = (const float*)d_in[15];
    const float* va_t  = (const float*)d_in[16];
    const float* Wih_s = (const float*)d_in[17];
    const float* Whh_s = (const float*)d_in[18];
    const float* bih_s = (const float*)d_in[19];
    const float* bhh_s = (const float*)d_in[20];
    const float* Wa_s  = (const float*)d_in[21];
    const float* va_s  = (const float*)d_in[22];
    const float* Wb    = (const float*)d_in[23];
    const float* bb    = (const float*)d_in[24];
    const float* Wbl   = (const float*)d_in[25];
    const float* bbl   = (const float*)d_in[26];
    const float* Wq    = (const float*)d_in[27];
    const float* bq    = (const float*)d_in[28];
    const float* Wk    = (const float*)d_in[29];
    const float* bk    = (const float*)d_in[30];
    const float* Wf    = (const float*)d_in[31];
    const float* bf_   = (const float*)d_in[32];

    float* ws = (float*)d_ws;
    float* news     = ws;              // 320000
    float* xprice   = ws + 320000;     // 32000
    float* tvec     = ws + 352000;     // 32000
    float* combined = ws + 384000;     // 32000
    float* qg       = ws + 416000;     // 32000
    float* kg       = ws + 448000;     // 32000
    float* out1     = ws + 480000;     // 1000
    float* gi       = ws + 481000;     // 38,400,000 floats (153.6 MB)
    float* dout = (float*)d_out;

    const size_t need = (size_t)(481000 + 38400000) * 4;
    if (ws_size >= need) {
        gi_gemm<<<Sn * 5, 256, 0, stream>>>(text, Wih_t, bih_t, gi);
        gru_text<<<Sn, 640, 0, stream>>>(gi, Whh_t, bhh_t, Wa_t, va_t, news);
    } else {
        text_enc<<<Sn * Dn, 256, 0, stream>>>(text, Wih_t, Whh_t, bih_t, bhh_t, Wa_t, va_t, news);
    }
    small_gru<FPn><<<Sn, 192, 0, stream>>>(price, Wih_p, Whh_p, bih_p, bhh_p, Wa_p, va_p, xprice);
    small_gru<Hn><<<Sn, 192, 0, stream>>>(news, Wih_s, Whh_s, bih_s, bhh_s, Wa_s, va_s, tvec);
    bilinear_head<<<Sn, 256, 0, stream>>>(Wb, bb, Wbl, bbl, Wq, bq, Wk, bk,
                                          xprice, tvec, combined, qg, kg, out1);
    mhsa<<<Sn, 256, 0, stream>>>(qg, kg, combined, Wf, bf_, out1, dout);
    loss_k<<<1, 512, 0, stream>>>(dout, label);
}